// Round 1
// baseline (387.485 us; speedup 1.0000x reference)
//
#include <hip/hip_runtime.h>

// Problem sizes (fixed): b=2, c=64, 48x48 -> n=2304, heads=4, hd=16, 3c=192
// n = 2304 = 9*256 exactly.

#define NEG_INF (-__builtin_huge_valf())

__device__ __forceinline__ unsigned f2key(float f) {
  unsigned u = __float_as_uint(f);
  return (u & 0x80000000u) ? ~u : (u | 0x80000000u);
}
__device__ __forceinline__ float key2f(unsigned k) {
  return (k & 0x80000000u) ? __uint_as_float(k & 0x7FFFFFFFu)
                           : __uint_as_float(~k);
}

__device__ __forceinline__ float dot16(const float4* q, float4 k0, float4 k1,
                                       float4 k2, float4 k3) {
  float s = q[0].x * k0.x;
  s = fmaf(q[0].y, k0.y, s); s = fmaf(q[0].z, k0.z, s); s = fmaf(q[0].w, k0.w, s);
  s = fmaf(q[1].x, k1.x, s); s = fmaf(q[1].y, k1.y, s);
  s = fmaf(q[1].z, k1.z, s); s = fmaf(q[1].w, k1.w, s);
  s = fmaf(q[2].x, k2.x, s); s = fmaf(q[2].y, k2.y, s);
  s = fmaf(q[2].z, k2.z, s); s = fmaf(q[2].w, k2.w, s);
  s = fmaf(q[3].x, k3.x, s); s = fmaf(q[3].y, k3.y, s);
  s = fmaf(q[3].z, k3.z, s); s = fmaf(q[3].w, k3.w, s);
  return s;
}

// K1: 1x1 conv qkv = Wqkv @ x + bqkv.  out[b,o,pos], grid = 2*192*9 blocks.
__global__ __launch_bounds__(256) void k_qkv(const float* __restrict__ x,
                                             const float* __restrict__ W,
                                             const float* __restrict__ bias,
                                             float* __restrict__ out) {
  int blk = blockIdx.x;
  int chunk = blk % 9;
  int o = (blk / 9) % 192;
  int b = blk / (9 * 192);
  int pos = chunk * 256 + threadIdx.x;
  const float* xb = x + b * 64 * 2304 + pos;
  const float* wr = W + o * 64;
  float acc = bias[o];
#pragma unroll
  for (int c = 0; c < 64; c++) acc = fmaf(wr[c], xb[c * 2304], acc);
  out[(b * 192 + o) * 2304 + pos] = acc;
}

// K2: 3x3 depthwise conv (SAME, correlation) + bias, scatter to head layout.
// q gets *0.25 (softmax scale folded in). dst[(b*4+head)*2304+pos)*16+d]
__global__ __launch_bounds__(256) void k_dw(const float* __restrict__ qkv,
                                            const float* __restrict__ Wpos,
                                            const float* __restrict__ bpos,
                                            float* __restrict__ qh,
                                            float* __restrict__ kh,
                                            float* __restrict__ vh) {
  int blk = blockIdx.x;
  int chunk = blk % 9;
  int ch = (blk / 9) % 192;
  int b = blk / (9 * 192);
  int pos = chunk * 256 + threadIdx.x;
  int yy = pos / 48, xx = pos % 48;
  const float* in = qkv + (b * 192 + ch) * 2304;
  const float* w = Wpos + ch * 9;
  float acc = bpos[ch];
#pragma unroll
  for (int dy = -1; dy <= 1; dy++) {
    int y2 = yy + dy;
    if ((unsigned)y2 < 48u) {
#pragma unroll
      for (int dx = -1; dx <= 1; dx++) {
        int x2 = xx + dx;
        if ((unsigned)x2 < 48u)
          acc = fmaf(w[(dy + 1) * 3 + (dx + 1)], in[y2 * 48 + x2], acc);
      }
    }
  }
  int sel = ch >> 6;
  int c = ch & 63;
  int head = c >> 4, d = c & 15;
  if (sel == 0) acc *= 0.25f;  // scale = hd^-0.5 = 0.25 folded into q
  float* dst = (sel == 0) ? qh : ((sel == 1) ? kh : vh);
  dst[((b * 4 + head) * 2304 + pos) * 16 + d] = acc;
}

// K3: entropy of full softmax per row, summed per (b,head) via atomicAdd.
// 4 rows / block, 256 threads, j = tid + 256*jj (jj<9). Online (m,s,u).
// entropy_row = log(S) - U/S with z = a - m, S = sum e^z, U = sum z e^z.
__global__ __launch_bounds__(256) void k_ent(const float* __restrict__ qh,
                                             const float* __restrict__ kh,
                                             float* __restrict__ ent) {
  int blk = blockIdx.x;
  int rowblk = blk % 576;
  int bh = blk / 576;
  int row0 = rowblk * 4;
  int tid = threadIdx.x, lane = tid & 63, wave = tid >> 6;
  const float4* qb = (const float4*)(qh + (bh * 2304 + row0) * 16);
  float4 qq[4][4];
#pragma unroll
  for (int r = 0; r < 4; r++)
#pragma unroll
    for (int p = 0; p < 4; p++) qq[r][p] = qb[r * 4 + p];
  const float4* kb = (const float4*)(kh + (size_t)bh * 2304 * 16);
  float m[4], s[4], u[4];
#pragma unroll
  for (int jj = 0; jj < 9; jj++) {
    int j = tid + jj * 256;
    float4 k0 = kb[j * 4 + 0], k1 = kb[j * 4 + 1];
    float4 k2 = kb[j * 4 + 2], k3 = kb[j * 4 + 3];
#pragma unroll
    for (int r = 0; r < 4; r++) {
      float a = dot16(qq[r], k0, k1, k2, k3);
      if (jj == 0) {
        m[r] = a; s[r] = 1.f; u[r] = 0.f;
      } else if (a > m[r]) {
        float d = m[r] - a, e = __expf(d);
        u[r] = e * fmaf(d, s[r], u[r]);
        s[r] = fmaf(e, s[r], 1.f);
        m[r] = a;
      } else {
        float z = a - m[r], e = __expf(z);
        s[r] += e;
        u[r] = fmaf(z, e, u[r]);
      }
    }
  }
  // butterfly merge across 64 lanes
#pragma unroll
  for (int off = 1; off < 64; off <<= 1) {
#pragma unroll
    for (int r = 0; r < 4; r++) {
      float m2 = __shfl_xor(m[r], off);
      float s2 = __shfl_xor(s[r], off);
      float u2 = __shfl_xor(u[r], off);
      float M = fmaxf(m[r], m2);
      float d1 = m[r] - M, d2 = m2 - M;
      float e1 = __expf(d1), e2 = __expf(d2);
      float ns = e1 * s[r] + e2 * s2;
      float nu = e1 * fmaf(d1, s[r], u[r]) + e2 * fmaf(d2, s2, u2);
      m[r] = M; s[r] = ns; u[r] = nu;
    }
  }
  __shared__ float sm[4][4], ss[4][4], su[4][4], er[4];
  if (lane == 0) {
#pragma unroll
    for (int r = 0; r < 4; r++) {
      sm[wave][r] = m[r]; ss[wave][r] = s[r]; su[wave][r] = u[r];
    }
  }
  __syncthreads();
  if (tid < 4) {
    int r = tid;
    float M = sm[0][r], S = ss[0][r], U = su[0][r];
#pragma unroll
    for (int w = 1; w < 4; w++) {
      float m2 = sm[w][r], s2 = ss[w][r], u2 = su[w][r];
      float Mn = fmaxf(M, m2);
      float d1 = M - Mn, d2 = m2 - Mn;
      float e1 = __expf(d1), e2 = __expf(d2);
      float S2 = e1 * S + e2 * s2;
      U = e1 * fmaf(d1, S, U) + e2 * fmaf(d2, s2, u2);
      S = S2; M = Mn;
    }
    er[r] = __logf(S) - U / S;
  }
  __syncthreads();
  if (tid == 0) atomicAdd(&ent[bh], er[0] + er[1] + er[2] + er[3]);
}

// K4: entropy gate MLP -> keep count per (b,head). 1 block.
__global__ void k_gate(const float* __restrict__ ent,
                       const float* __restrict__ Wg1,
                       const float* __restrict__ bg1,
                       const float* __restrict__ Wg2,
                       const float* __restrict__ bg2,
                       int* __restrict__ keepArr) {
  int t = threadIdx.x;
  if (t < 8) {
    float e = ent[t] * (1.f / 2304.f);
    float acc = bg2[0];
#pragma unroll
    for (int i = 0; i < 16; i++) {
      float h = fmaxf(fmaf(e, Wg1[i], bg1[i]), 0.f);
      acc = fmaf(h, Wg2[i], acc);
    }
    float ratio = 0.9f / (1.f + __expf(-acc)) + 0.1f;
    int kp = (int)ceilf(ratio * 2304.f);
    kp = min(max(kp, 1), 2304);
    keepArr[t] = kp;
  }
}

// K5: per-row exact top-k threshold (radix select on fp32 bit keys) +
// masked softmax + PV. 4 rows/block, 256 threads.
__global__ __launch_bounds__(256) void k_attn(const float* __restrict__ qh,
                                              const float* __restrict__ kh,
                                              const float* __restrict__ vh,
                                              const int* __restrict__ keepArr,
                                              float* __restrict__ oh) {
  __shared__ float aLds[4 * 2304];  // logits; reused as reduce buffer later
  __shared__ unsigned hist[256];
  __shared__ float mSh[4][4];
  __shared__ unsigned selB[2];
  __shared__ float outSh[64];
  __shared__ float sSum[4];

  int blk = blockIdx.x;
  int rowblk = blk % 576;
  int bh = blk / 576;
  int row0 = rowblk * 4;
  int tid = threadIdx.x, lane = tid & 63, wave = tid >> 6;

  const float4* qb = (const float4*)(qh + (bh * 2304 + row0) * 16);
  const float4* kb = (const float4*)(kh + (size_t)bh * 2304 * 16);
  const float4* vb = (const float4*)(vh + (size_t)bh * 2304 * 16);

  // ---- phase A: logits a[r][j] for 4 rows; row max ----
  float4 qq[4][4];
#pragma unroll
  for (int r = 0; r < 4; r++)
#pragma unroll
    for (int p = 0; p < 4; p++) qq[r][p] = qb[r * 4 + p];

  float a[4][9];
  float mloc[4] = {NEG_INF, NEG_INF, NEG_INF, NEG_INF};
#pragma unroll
  for (int jj = 0; jj < 9; jj++) {
    int j = tid + jj * 256;
    float4 k0 = kb[j * 4 + 0], k1 = kb[j * 4 + 1];
    float4 k2 = kb[j * 4 + 2], k3 = kb[j * 4 + 3];
#pragma unroll
    for (int r = 0; r < 4; r++) {
      float v = dot16(qq[r], k0, k1, k2, k3);
      a[r][jj] = v;
      mloc[r] = fmaxf(mloc[r], v);
      aLds[r * 2304 + j] = v;
    }
  }
#pragma unroll
  for (int off = 1; off < 64; off <<= 1)
#pragma unroll
    for (int r = 0; r < 4; r++)
      mloc[r] = fmaxf(mloc[r], __shfl_xor(mloc[r], off));
  if (lane == 0) {
#pragma unroll
    for (int r = 0; r < 4; r++) mSh[wave][r] = mloc[r];
  }
  __syncthreads();
  float m[4];
#pragma unroll
  for (int r = 0; r < 4; r++)
    m[r] = fmaxf(fmaxf(mSh[0][r], mSh[1][r]), fmaxf(mSh[2][r], mSh[3][r]));

  unsigned keep = (unsigned)keepArr[bh];

  // ---- phase B: radix select keep-th largest per row -> threshold ----
  float th[4];
#pragma unroll
  for (int r = 0; r < 4; r++) {
    unsigned rem = keep, prefix = 0u;
    for (int pass = 0; pass < 4; pass++) {
      int shift = 24 - pass * 8;
      hist[tid] = 0u;
      __syncthreads();
      unsigned hm = (pass == 0) ? 0u : (0xFFFFFFFFu << (shift + 8));
#pragma unroll
      for (int jj = 0; jj < 9; jj++) {
        unsigned kk = f2key(a[r][jj]);
        if ((kk & hm) == prefix) atomicAdd(&hist[(kk >> shift) & 255u], 1u);
      }
      __syncthreads();
      if (tid < 64) {
        unsigned h0 = hist[tid * 4 + 0], h1 = hist[tid * 4 + 1];
        unsigned h2 = hist[tid * 4 + 2], h3 = hist[tid * 4 + 3];
        unsigned gs = h0 + h1 + h2 + h3;
        unsigned cur = gs;
#pragma unroll
        for (int off = 1; off < 64; off <<= 1) {
          unsigned vv = __shfl_down(cur, off);
          if (lane + off < 64) cur += vv;
        }
        unsigned above = cur - gs;  // suffix count strictly above this lane's 4 buckets
        if (cur >= rem && above < rem) {
          unsigned sfx3 = above + h3, sfx2 = sfx3 + h2, sfx1 = sfx2 + h1;
          unsigned bket, nrem;
          if (sfx3 >= rem)      { bket = 3u; nrem = rem - above; }
          else if (sfx2 >= rem) { bket = 2u; nrem = rem - sfx3; }
          else if (sfx1 >= rem) { bket = 1u; nrem = rem - sfx2; }
          else                  { bket = 0u; nrem = rem - sfx1; }
          selB[0] = (unsigned)tid * 4u + bket;
          selB[1] = nrem;
        }
      }
      __syncthreads();
      prefix |= selB[0] << shift;
      rem = selB[1];
      // next pass's hist-clear barrier protects selB before rewrite
    }
    th[r] = key2f(prefix);
  }

  // ---- phase C: masked softmax + PV, d-quad split ----
  int dg = tid & 3, jg = tid >> 2;
  float acc[4][4];
#pragma unroll
  for (int r = 0; r < 4; r++)
#pragma unroll
    for (int i = 0; i < 4; i++) acc[r][i] = 0.f;
  float sp[4] = {0.f, 0.f, 0.f, 0.f};
  for (int jj = 0; jj < 36; jj++) {
    int j = jg + jj * 64;
    float4 v4 = vb[j * 4 + dg];
#pragma unroll
    for (int r = 0; r < 4; r++) {
      float av = aLds[r * 2304 + j];
      if (av >= th[r]) {
        float p = __expf(av - m[r]);
        if (dg == 0) sp[r] += p;
        acc[r][0] = fmaf(p, v4.x, acc[r][0]);
        acc[r][1] = fmaf(p, v4.y, acc[r][1]);
        acc[r][2] = fmaf(p, v4.z, acc[r][2]);
        acc[r][3] = fmaf(p, v4.w, acc[r][3]);
      }
    }
  }

  // ---- phase D: reduce over 64 j-groups via padded LDS ----
  __syncthreads();  // all aLds reads done; safe to reuse as 'part'
  float* part = aLds;  // stride 69 floats per j-group; idx r*16+dg*4+di, s at 64+r
#pragma unroll
  for (int r = 0; r < 4; r++)
#pragma unroll
    for (int i = 0; i < 4; i++)
      part[jg * 69 + r * 16 + dg * 4 + i] = acc[r][i];
  if (dg == 0) {
#pragma unroll
    for (int r = 0; r < 4; r++) part[jg * 69 + 64 + r] = sp[r];
  }
  __syncthreads();
  if (tid < 68) {
    float t2 = 0.f;
    for (int g = 0; g < 64; g++) t2 += part[g * 69 + tid];
    if (tid < 64) outSh[tid] = t2;
    else sSum[tid - 64] = t2;
  }
  __syncthreads();
  if (tid < 64) {
    int r = tid >> 4, d = tid & 15;
    oh[((size_t)(bh * 2304 + row0 + r)) * 16 + d] = outSh[tid] / sSum[r];
  }
}

// K6: output projection out[b,co,pos] = Wproj @ heads + bproj
__global__ __launch_bounds__(256) void k_proj(const float* __restrict__ oh,
                                              const float* __restrict__ Wp,
                                              const float* __restrict__ bp,
                                              float* __restrict__ out) {
  int blk = blockIdx.x;
  int chunk = blk % 9;
  int co = (blk / 9) % 64;
  int b = blk / (9 * 64);
  int pos = chunk * 256 + threadIdx.x;
  const float* wr = Wp + co * 64;
  float acc = bp[co];
#pragma unroll
  for (int head = 0; head < 4; head++) {
    const float4* op = (const float4*)(oh + ((size_t)((b * 4 + head) * 2304 + pos)) * 16);
#pragma unroll
    for (int p = 0; p < 4; p++) {
      float4 o4 = op[p];
      acc = fmaf(wr[head * 16 + p * 4 + 0], o4.x, acc);
      acc = fmaf(wr[head * 16 + p * 4 + 1], o4.y, acc);
      acc = fmaf(wr[head * 16 + p * 4 + 2], o4.z, acc);
      acc = fmaf(wr[head * 16 + p * 4 + 3], o4.w, acc);
    }
  }
  out[(b * 64 + co) * 2304 + pos] = acc;
}

extern "C" void kernel_launch(void* const* d_in, const int* in_sizes, int n_in,
                              void* d_out, int out_size, void* d_ws,
                              size_t ws_size, hipStream_t stream) {
  const float* x    = (const float*)d_in[0];
  const float* Wqkv = (const float*)d_in[1];
  const float* bqkv = (const float*)d_in[2];
  const float* Wpos = (const float*)d_in[3];
  const float* bpos = (const float*)d_in[4];
  const float* Wg1  = (const float*)d_in[5];
  const float* bg1  = (const float*)d_in[6];
  const float* Wg2  = (const float*)d_in[7];
  const float* bg2  = (const float*)d_in[8];
  const float* Wpr  = (const float*)d_in[9];
  const float* bpr  = (const float*)d_in[10];
  float* out = (float*)d_out;

  float* ws = (float*)d_ws;
  float* qkv_raw = ws;                // 2*192*2304 = 884736
  float* qh = qkv_raw + 884736;       // 294912 (pre-scaled by 0.25)
  float* kh = qh + 294912;            // 294912
  float* vh = kh + 294912;            // 294912
  float* oh = vh + 294912;            // 294912
  float* ent = oh + 294912;           // 8
  int* keep = (int*)(ent + 8);        // 8

  hipMemsetAsync(ent, 0, 8 * sizeof(float), stream);
  hipLaunchKernelGGL(k_qkv, dim3(2 * 192 * 9), dim3(256), 0, stream,
                     x, Wqkv, bqkv, qkv_raw);
  hipLaunchKernelGGL(k_dw, dim3(2 * 192 * 9), dim3(256), 0, stream,
                     qkv_raw, Wpos, bpos, qh, kh, vh);
  hipLaunchKernelGGL(k_ent, dim3(8 * 576), dim3(256), 0, stream, qh, kh, ent);
  hipLaunchKernelGGL(k_gate, dim3(1), dim3(64), 0, stream,
                     ent, Wg1, bg1, Wg2, bg2, keep);
  hipLaunchKernelGGL(k_attn, dim3(8 * 576), dim3(256), 0, stream,
                     qh, kh, vh, keep, oh);
  hipLaunchKernelGGL(k_proj, dim3(2 * 64 * 9), dim3(256), 0, stream,
                     oh, Wpr, bpr, out);
}

// Round 2
// 359.479 us; speedup vs baseline: 1.0779x; 1.0779x over previous
//
#include <hip/hip_runtime.h>

// Problem sizes (fixed): b=2, c=64, 48x48 -> n=2304, heads=4, hd=16, 3c=192
// n = 2304 = 9*256 exactly.

#define NEG_INF (-__builtin_huge_valf())

__device__ __forceinline__ unsigned f2key(float f) {
  unsigned u = __float_as_uint(f);
  return (u & 0x80000000u) ? ~u : (u | 0x80000000u);
}
__device__ __forceinline__ float key2f(unsigned k) {
  return (k & 0x80000000u) ? __uint_as_float(k & 0x7FFFFFFFu)
                           : __uint_as_float(~k);
}

__device__ __forceinline__ float dot16(const float4* q, float4 k0, float4 k1,
                                       float4 k2, float4 k3) {
  float s = q[0].x * k0.x;
  s = fmaf(q[0].y, k0.y, s); s = fmaf(q[0].z, k0.z, s); s = fmaf(q[0].w, k0.w, s);
  s = fmaf(q[1].x, k1.x, s); s = fmaf(q[1].y, k1.y, s);
  s = fmaf(q[1].z, k1.z, s); s = fmaf(q[1].w, k1.w, s);
  s = fmaf(q[2].x, k2.x, s); s = fmaf(q[2].y, k2.y, s);
  s = fmaf(q[2].z, k2.z, s); s = fmaf(q[2].w, k2.w, s);
  s = fmaf(q[3].x, k3.x, s); s = fmaf(q[3].y, k3.y, s);
  s = fmaf(q[3].z, k3.z, s); s = fmaf(q[3].w, k3.w, s);
  return s;
}

// K1: 1x1 conv qkv = Wqkv @ x + bqkv.  out[b,o,pos], grid = 2*192*9 blocks.
__global__ __launch_bounds__(256) void k_qkv(const float* __restrict__ x,
                                             const float* __restrict__ W,
                                             const float* __restrict__ bias,
                                             float* __restrict__ out) {
  int blk = blockIdx.x;
  int chunk = blk % 9;
  int o = (blk / 9) % 192;
  int b = blk / (9 * 192);
  int pos = chunk * 256 + threadIdx.x;
  const float* xb = x + b * 64 * 2304 + pos;
  const float* wr = W + o * 64;
  float acc = bias[o];
#pragma unroll
  for (int c = 0; c < 64; c++) acc = fmaf(wr[c], xb[c * 2304], acc);
  out[(b * 192 + o) * 2304 + pos] = acc;
}

// K2: 3x3 depthwise conv (SAME) + bias, scatter to head layout.
// q gets *0.25 (softmax scale folded in).
__global__ __launch_bounds__(256) void k_dw(const float* __restrict__ qkv,
                                            const float* __restrict__ Wpos,
                                            const float* __restrict__ bpos,
                                            float* __restrict__ qh,
                                            float* __restrict__ kh,
                                            float* __restrict__ vh) {
  int blk = blockIdx.x;
  int chunk = blk % 9;
  int ch = (blk / 9) % 192;
  int b = blk / (9 * 192);
  int pos = chunk * 256 + threadIdx.x;
  int yy = pos / 48, xx = pos % 48;
  const float* in = qkv + (b * 192 + ch) * 2304;
  const float* w = Wpos + ch * 9;
  float acc = bpos[ch];
#pragma unroll
  for (int dy = -1; dy <= 1; dy++) {
    int y2 = yy + dy;
    if ((unsigned)y2 < 48u) {
#pragma unroll
      for (int dx = -1; dx <= 1; dx++) {
        int x2 = xx + dx;
        if ((unsigned)x2 < 48u)
          acc = fmaf(w[(dy + 1) * 3 + (dx + 1)], in[y2 * 48 + x2], acc);
      }
    }
  }
  int sel = ch >> 6;
  int c = ch & 63;
  int head = c >> 4, d = c & 15;
  if (sel == 0) acc *= 0.25f;  // scale = hd^-0.5 = 0.25 folded into q
  float* dst = (sel == 0) ? qh : ((sel == 1) ? kh : vh);
  dst[((b * 4 + head) * 2304 + pos) * 16 + d] = acc;
}

// K3: entropy of full softmax per row, summed per (b,head) via atomicAdd.
// Branchless two-pass: register-held logits, exact row max, then fixed-m sums.
// entropy_row = log(S) - U/S with z = a - m, S = sum e^z, U = sum z e^z.
__global__ __launch_bounds__(256) void k_ent(const float* __restrict__ qh,
                                             const float* __restrict__ kh,
                                             float* __restrict__ ent) {
  int blk = blockIdx.x;
  int rowblk = blk % 576;
  int bh = blk / 576;
  int row0 = rowblk * 4;
  int tid = threadIdx.x, lane = tid & 63, wave = tid >> 6;
  const float4* qb = (const float4*)(qh + (bh * 2304 + row0) * 16);
  float4 qq[4][4];
#pragma unroll
  for (int r = 0; r < 4; r++)
#pragma unroll
    for (int p = 0; p < 4; p++) qq[r][p] = qb[r * 4 + p];
  const float4* kb = (const float4*)(kh + (size_t)bh * 2304 * 16);

  float a[4][9];
  float mloc[4] = {NEG_INF, NEG_INF, NEG_INF, NEG_INF};
#pragma unroll
  for (int jj = 0; jj < 9; jj++) {
    int j = tid + jj * 256;
    float4 k0 = kb[j * 4 + 0], k1 = kb[j * 4 + 1];
    float4 k2 = kb[j * 4 + 2], k3 = kb[j * 4 + 3];
#pragma unroll
    for (int r = 0; r < 4; r++) {
      float v = dot16(qq[r], k0, k1, k2, k3);
      a[r][jj] = v;
      mloc[r] = fmaxf(mloc[r], v);
    }
  }
#pragma unroll
  for (int off = 1; off < 64; off <<= 1)
#pragma unroll
    for (int r = 0; r < 4; r++)
      mloc[r] = fmaxf(mloc[r], __shfl_xor(mloc[r], off));

  __shared__ float mSh[4][4], sSh[4][4], uSh[4][4], er[4];
  if (lane == 0) {
#pragma unroll
    for (int r = 0; r < 4; r++) mSh[wave][r] = mloc[r];
  }
  __syncthreads();
  float m[4];
#pragma unroll
  for (int r = 0; r < 4; r++)
    m[r] = fmaxf(fmaxf(mSh[0][r], mSh[1][r]), fmaxf(mSh[2][r], mSh[3][r]));

  float s[4] = {0.f, 0.f, 0.f, 0.f}, u[4] = {0.f, 0.f, 0.f, 0.f};
#pragma unroll
  for (int jj = 0; jj < 9; jj++) {
#pragma unroll
    for (int r = 0; r < 4; r++) {
      float z = a[r][jj] - m[r];
      float e = __expf(z);
      s[r] += e;
      u[r] = fmaf(z, e, u[r]);
    }
  }
#pragma unroll
  for (int off = 1; off < 64; off <<= 1) {
#pragma unroll
    for (int r = 0; r < 4; r++) {
      s[r] += __shfl_xor(s[r], off);
      u[r] += __shfl_xor(u[r], off);
    }
  }
  if (lane == 0) {
#pragma unroll
    for (int r = 0; r < 4; r++) { sSh[wave][r] = s[r]; uSh[wave][r] = u[r]; }
  }
  __syncthreads();
  if (tid < 4) {
    int r = tid;
    float S = sSh[0][r] + sSh[1][r] + sSh[2][r] + sSh[3][r];
    float U = uSh[0][r] + uSh[1][r] + uSh[2][r] + uSh[3][r];
    er[r] = __logf(S) - U / S;
  }
  __syncthreads();
  if (tid == 0) atomicAdd(&ent[bh], er[0] + er[1] + er[2] + er[3]);
}

// K5: gate MLP (inline, uniform) + per-row exact top-k threshold via
// row-per-wave ballot bit-search + masked softmax + PV. 4 rows/block.
__global__ __launch_bounds__(256) void k_attn(const float* __restrict__ qh,
                                              const float* __restrict__ kh,
                                              const float* __restrict__ vh,
                                              const float* __restrict__ ent,
                                              const float* __restrict__ Wg1,
                                              const float* __restrict__ bg1,
                                              const float* __restrict__ Wg2,
                                              const float* __restrict__ bg2,
                                              float* __restrict__ oh) {
  __shared__ float aLds[4 * 2304];  // logits; reused as reduce buffer later
  __shared__ float mSh[4][4];
  __shared__ float thSh[4];
  __shared__ float outSh[64];
  __shared__ float sSum[4];

  int blk = blockIdx.x;
  int rowblk = blk % 576;
  int bh = blk / 576;
  int row0 = rowblk * 4;
  int tid = threadIdx.x, lane = tid & 63, wave = tid >> 6;

  const float4* qb = (const float4*)(qh + (bh * 2304 + row0) * 16);
  const float4* kb = (const float4*)(kh + (size_t)bh * 2304 * 16);
  const float4* vb = (const float4*)(vh + (size_t)bh * 2304 * 16);

  // ---- gate MLP: keep count (uniform across block; same ent for all) ----
  float eAvg = ent[bh] * (1.f / 2304.f);
  float gacc = bg2[0];
#pragma unroll
  for (int i = 0; i < 16; i++) {
    float h = fmaxf(fmaf(eAvg, Wg1[i], bg1[i]), 0.f);
    gacc = fmaf(h, Wg2[i], gacc);
  }
  float ratio = 0.9f / (1.f + __expf(-gacc)) + 0.1f;
  int kp = (int)ceilf(ratio * 2304.f);
  unsigned keep = (unsigned)min(max(kp, 1), 2304);

  // ---- phase A: logits -> LDS; row max ----
  float4 qq[4][4];
#pragma unroll
  for (int r = 0; r < 4; r++)
#pragma unroll
    for (int p = 0; p < 4; p++) qq[r][p] = qb[r * 4 + p];

  float mloc[4] = {NEG_INF, NEG_INF, NEG_INF, NEG_INF};
#pragma unroll
  for (int jj = 0; jj < 9; jj++) {
    int j = tid + jj * 256;
    float4 k0 = kb[j * 4 + 0], k1 = kb[j * 4 + 1];
    float4 k2 = kb[j * 4 + 2], k3 = kb[j * 4 + 3];
#pragma unroll
    for (int r = 0; r < 4; r++) {
      float v = dot16(qq[r], k0, k1, k2, k3);
      mloc[r] = fmaxf(mloc[r], v);
      aLds[r * 2304 + j] = v;
    }
  }
#pragma unroll
  for (int off = 1; off < 64; off <<= 1)
#pragma unroll
    for (int r = 0; r < 4; r++)
      mloc[r] = fmaxf(mloc[r], __shfl_xor(mloc[r], off));
  if (lane == 0) {
#pragma unroll
    for (int r = 0; r < 4; r++) mSh[wave][r] = mloc[r];
  }
  __syncthreads();
  float m[4];
#pragma unroll
  for (int r = 0; r < 4; r++)
    m[r] = fmaxf(fmaxf(mSh[0][r], mSh[1][r]), fmaxf(mSh[2][r], mSh[3][r]));

  // ---- phase B: row-per-wave exact k-th largest via ballot bit-search ----
  {
    int r = wave;  // each wave owns one row
    unsigned keys[36];
    const float* rowp = aLds + r * 2304 + lane;
#pragma unroll
    for (int i = 0; i < 36; i++) keys[i] = f2key(rowp[i * 64]);
    unsigned T = 0u;
    for (int bit = 31; bit >= 0; --bit) {
      unsigned cand = T | (1u << bit);
      unsigned cnt = 0u;
#pragma unroll
      for (int i = 0; i < 36; i++)
        cnt += (unsigned)__popcll(__ballot(keys[i] >= cand));
      if (cnt >= keep) T = cand;  // uniform
    }
    if (lane == 0) thSh[r] = key2f(T);
  }
  __syncthreads();
  float th[4];
#pragma unroll
  for (int r = 0; r < 4; r++) th[r] = thSh[r];

  // ---- phase C: masked softmax + PV, d-quad split ----
  int dg = tid & 3, jg = tid >> 2;
  float acc[4][4];
#pragma unroll
  for (int r = 0; r < 4; r++)
#pragma unroll
    for (int i = 0; i < 4; i++) acc[r][i] = 0.f;
  float sp[4] = {0.f, 0.f, 0.f, 0.f};
  for (int jj = 0; jj < 36; jj++) {
    int j = jg + jj * 64;
    float4 v4 = vb[j * 4 + dg];
#pragma unroll
    for (int r = 0; r < 4; r++) {
      float av = aLds[r * 2304 + j];
      if (av >= th[r]) {
        float p = __expf(av - m[r]);
        if (dg == 0) sp[r] += p;
        acc[r][0] = fmaf(p, v4.x, acc[r][0]);
        acc[r][1] = fmaf(p, v4.y, acc[r][1]);
        acc[r][2] = fmaf(p, v4.z, acc[r][2]);
        acc[r][3] = fmaf(p, v4.w, acc[r][3]);
      }
    }
  }

  // ---- phase D: reduce over 64 j-groups via padded LDS ----
  __syncthreads();  // all aLds reads done; safe to reuse as 'part'
  float* part = aLds;  // stride 69 floats per j-group
#pragma unroll
  for (int r = 0; r < 4; r++)
#pragma unroll
    for (int i = 0; i < 4; i++)
      part[jg * 69 + r * 16 + dg * 4 + i] = acc[r][i];
  if (dg == 0) {
#pragma unroll
    for (int r = 0; r < 4; r++) part[jg * 69 + 64 + r] = sp[r];
  }
  __syncthreads();
  if (tid < 68) {
    float t2 = 0.f;
    for (int g = 0; g < 64; g++) t2 += part[g * 69 + tid];
    if (tid < 64) outSh[tid] = t2;
    else sSum[tid - 64] = t2;
  }
  __syncthreads();
  if (tid < 64) {
    int r = tid >> 4, d = tid & 15;
    oh[((size_t)(bh * 2304 + row0 + r)) * 16 + d] = outSh[tid] / sSum[r];
  }
}

// K6: output projection out[b,co,pos] = Wproj @ heads + bproj
__global__ __launch_bounds__(256) void k_proj(const float* __restrict__ oh,
                                              const float* __restrict__ Wp,
                                              const float* __restrict__ bp,
                                              float* __restrict__ out) {
  int blk = blockIdx.x;
  int chunk = blk % 9;
  int co = (blk / 9) % 64;
  int b = blk / (9 * 64);
  int pos = chunk * 256 + threadIdx.x;
  const float* wr = Wp + co * 64;
  float acc = bp[co];
#pragma unroll
  for (int head = 0; head < 4; head++) {
    const float4* op = (const float4*)(oh + ((size_t)((b * 4 + head) * 2304 + pos)) * 16);
#pragma unroll
    for (int p = 0; p < 4; p++) {
      float4 o4 = op[p];
      acc = fmaf(wr[head * 16 + p * 4 + 0], o4.x, acc);
      acc = fmaf(wr[head * 16 + p * 4 + 1], o4.y, acc);
      acc = fmaf(wr[head * 16 + p * 4 + 2], o4.z, acc);
      acc = fmaf(wr[head * 16 + p * 4 + 3], o4.w, acc);
    }
  }
  out[(b * 64 + co) * 2304 + pos] = acc;
}

extern "C" void kernel_launch(void* const* d_in, const int* in_sizes, int n_in,
                              void* d_out, int out_size, void* d_ws,
                              size_t ws_size, hipStream_t stream) {
  const float* x    = (const float*)d_in[0];
  const float* Wqkv = (const float*)d_in[1];
  const float* bqkv = (const float*)d_in[2];
  const float* Wpos = (const float*)d_in[3];
  const float* bpos = (const float*)d_in[4];
  const float* Wg1  = (const float*)d_in[5];
  const float* bg1  = (const float*)d_in[6];
  const float* Wg2  = (const float*)d_in[7];
  const float* bg2  = (const float*)d_in[8];
  const float* Wpr  = (const float*)d_in[9];
  const float* bpr  = (const float*)d_in[10];
  float* out = (float*)d_out;

  float* ws = (float*)d_ws;
  float* qkv_raw = ws;                // 2*192*2304 = 884736
  float* qh = qkv_raw + 884736;       // 294912 (pre-scaled by 0.25)
  float* kh = qh + 294912;            // 294912
  float* vh = kh + 294912;            // 294912
  float* oh = vh + 294912;            // 294912
  float* ent = oh + 294912;           // 8

  hipMemsetAsync(ent, 0, 8 * sizeof(float), stream);
  hipLaunchKernelGGL(k_qkv, dim3(2 * 192 * 9), dim3(256), 0, stream,
                     x, Wqkv, bqkv, qkv_raw);
  hipLaunchKernelGGL(k_dw, dim3(2 * 192 * 9), dim3(256), 0, stream,
                     qkv_raw, Wpos, bpos, qh, kh, vh);
  hipLaunchKernelGGL(k_ent, dim3(8 * 576), dim3(256), 0, stream, qh, kh, ent);
  hipLaunchKernelGGL(k_attn, dim3(8 * 576), dim3(256), 0, stream,
                     qh, kh, vh, ent, Wg1, bg1, Wg2, bg2, oh);
  hipLaunchKernelGGL(k_proj, dim3(2 * 64 * 9), dim3(256), 0, stream,
                     oh, Wpr, bpr, out);
}

// Round 3
// 312.258 us; speedup vs baseline: 1.2409x; 1.1512x over previous
//
#include <hip/hip_runtime.h>

// Problem sizes (fixed): b=2, c=64, 48x48 -> n=2304, heads=4, hd=16, 3c=192
// n = 2304 = 9*256 exactly.

#define NEG_INF (-__builtin_huge_valf())

__device__ __forceinline__ unsigned f2key(float f) {
  unsigned u = __float_as_uint(f);
  return (u & 0x80000000u) ? ~u : (u | 0x80000000u);
}
__device__ __forceinline__ float key2f(unsigned k) {
  return (k & 0x80000000u) ? __uint_as_float(k & 0x7FFFFFFFu)
                           : __uint_as_float(~k);
}

__device__ __forceinline__ float dot16(const float4* q, float4 k0, float4 k1,
                                       float4 k2, float4 k3) {
  float s = q[0].x * k0.x;
  s = fmaf(q[0].y, k0.y, s); s = fmaf(q[0].z, k0.z, s); s = fmaf(q[0].w, k0.w, s);
  s = fmaf(q[1].x, k1.x, s); s = fmaf(q[1].y, k1.y, s);
  s = fmaf(q[1].z, k1.z, s); s = fmaf(q[1].w, k1.w, s);
  s = fmaf(q[2].x, k2.x, s); s = fmaf(q[2].y, k2.y, s);
  s = fmaf(q[2].z, k2.z, s); s = fmaf(q[2].w, k2.w, s);
  s = fmaf(q[3].x, k3.x, s); s = fmaf(q[3].y, k3.y, s);
  s = fmaf(q[3].z, k3.z, s); s = fmaf(q[3].w, k3.w, s);
  return s;
}

// K1: 1x1 conv qkv = Wqkv @ x + bqkv.  out[b,o,pos], grid = 2*192*9 blocks.
__global__ __launch_bounds__(256) void k_qkv(const float* __restrict__ x,
                                             const float* __restrict__ W,
                                             const float* __restrict__ bias,
                                             float* __restrict__ out) {
  int blk = blockIdx.x;
  int chunk = blk % 9;
  int o = (blk / 9) % 192;
  int b = blk / (9 * 192);
  int pos = chunk * 256 + threadIdx.x;
  const float* xb = x + b * 64 * 2304 + pos;
  const float* wr = W + o * 64;
  float acc = bias[o];
#pragma unroll
  for (int c = 0; c < 64; c++) acc = fmaf(wr[c], xb[c * 2304], acc);
  out[(b * 192 + o) * 2304 + pos] = acc;
}

// K2: 3x3 depthwise conv (SAME) + bias, scatter to head layout.
// q gets *0.25 (softmax scale folded in).
__global__ __launch_bounds__(256) void k_dw(const float* __restrict__ qkv,
                                            const float* __restrict__ Wpos,
                                            const float* __restrict__ bpos,
                                            float* __restrict__ qh,
                                            float* __restrict__ kh,
                                            float* __restrict__ vh) {
  int blk = blockIdx.x;
  int chunk = blk % 9;
  int ch = (blk / 9) % 192;
  int b = blk / (9 * 192);
  int pos = chunk * 256 + threadIdx.x;
  int yy = pos / 48, xx = pos % 48;
  const float* in = qkv + (b * 192 + ch) * 2304;
  const float* w = Wpos + ch * 9;
  float acc = bpos[ch];
#pragma unroll
  for (int dy = -1; dy <= 1; dy++) {
    int y2 = yy + dy;
    if ((unsigned)y2 < 48u) {
#pragma unroll
      for (int dx = -1; dx <= 1; dx++) {
        int x2 = xx + dx;
        if ((unsigned)x2 < 48u)
          acc = fmaf(w[(dy + 1) * 3 + (dx + 1)], in[y2 * 48 + x2], acc);
      }
    }
  }
  int sel = ch >> 6;
  int c = ch & 63;
  int head = c >> 4, d = c & 15;
  if (sel == 0) acc *= 0.25f;  // scale = hd^-0.5 = 0.25 folded into q
  float* dst = (sel == 0) ? qh : ((sel == 1) ? kh : vh);
  dst[((b * 4 + head) * 2304 + pos) * 16 + d] = acc;
}

// K3: entropy of full softmax per row, summed per (b,head) via atomicAdd.
// Branchless two-pass: register-held logits, exact row max, then fixed-m sums.
__global__ __launch_bounds__(256) void k_ent(const float* __restrict__ qh,
                                             const float* __restrict__ kh,
                                             float* __restrict__ ent) {
  int blk = blockIdx.x;
  int rowblk = blk % 576;
  int bh = blk / 576;
  int row0 = rowblk * 4;
  int tid = threadIdx.x, lane = tid & 63, wave = tid >> 6;
  const float4* qb = (const float4*)(qh + (bh * 2304 + row0) * 16);
  float4 qq[4][4];
#pragma unroll
  for (int r = 0; r < 4; r++)
#pragma unroll
    for (int p = 0; p < 4; p++) qq[r][p] = qb[r * 4 + p];
  const float4* kb = (const float4*)(kh + (size_t)bh * 2304 * 16);

  float a[4][9];
  float mloc[4] = {NEG_INF, NEG_INF, NEG_INF, NEG_INF};
#pragma unroll
  for (int jj = 0; jj < 9; jj++) {
    int j = tid + jj * 256;
    float4 k0 = kb[j * 4 + 0], k1 = kb[j * 4 + 1];
    float4 k2 = kb[j * 4 + 2], k3 = kb[j * 4 + 3];
#pragma unroll
    for (int r = 0; r < 4; r++) {
      float v = dot16(qq[r], k0, k1, k2, k3);
      a[r][jj] = v;
      mloc[r] = fmaxf(mloc[r], v);
    }
  }
#pragma unroll
  for (int off = 1; off < 64; off <<= 1)
#pragma unroll
    for (int r = 0; r < 4; r++)
      mloc[r] = fmaxf(mloc[r], __shfl_xor(mloc[r], off));

  __shared__ float mSh[4][4], sSh[4][4], uSh[4][4], er[4];
  if (lane == 0) {
#pragma unroll
    for (int r = 0; r < 4; r++) mSh[wave][r] = mloc[r];
  }
  __syncthreads();
  float m[4];
#pragma unroll
  for (int r = 0; r < 4; r++)
    m[r] = fmaxf(fmaxf(mSh[0][r], mSh[1][r]), fmaxf(mSh[2][r], mSh[3][r]));

  float s[4] = {0.f, 0.f, 0.f, 0.f}, u[4] = {0.f, 0.f, 0.f, 0.f};
#pragma unroll
  for (int jj = 0; jj < 9; jj++) {
#pragma unroll
    for (int r = 0; r < 4; r++) {
      float z = a[r][jj] - m[r];
      float e = __expf(z);
      s[r] += e;
      u[r] = fmaf(z, e, u[r]);
    }
  }
#pragma unroll
  for (int off = 1; off < 64; off <<= 1) {
#pragma unroll
    for (int r = 0; r < 4; r++) {
      s[r] += __shfl_xor(s[r], off);
      u[r] += __shfl_xor(u[r], off);
    }
  }
  if (lane == 0) {
#pragma unroll
    for (int r = 0; r < 4; r++) { sSh[wave][r] = s[r]; uSh[wave][r] = u[r]; }
  }
  __syncthreads();
  if (tid < 4) {
    int r = tid;
    float S = sSh[0][r] + sSh[1][r] + sSh[2][r] + sSh[3][r];
    float U = uSh[0][r] + uSh[1][r] + uSh[2][r] + uSh[3][r];
    er[r] = __logf(S) - U / S;
  }
  __syncthreads();
  if (tid == 0) atomicAdd(&ent[bh], er[0] + er[1] + er[2] + er[3]);
}

// K5: gate MLP (inline, uniform) + per-row exact top-k threshold via
// row-per-wave ballot bit-search (early exit) + masked softmax + PV.
__global__ __launch_bounds__(256) void k_attn(const float* __restrict__ qh,
                                              const float* __restrict__ kh,
                                              const float* __restrict__ vh,
                                              const float* __restrict__ ent,
                                              const float* __restrict__ Wg1,
                                              const float* __restrict__ bg1,
                                              const float* __restrict__ Wg2,
                                              const float* __restrict__ bg2,
                                              float* __restrict__ oh) {
  __shared__ float aLds[4 * 2304];  // logits -> probs -> reduce buffer
  __shared__ float mSh[4][4];
  __shared__ float thSh[4];
  __shared__ float sShW[4][4];

  int blk = blockIdx.x;
  int rowblk = blk % 576;
  int bh = blk / 576;
  int row0 = rowblk * 4;
  int tid = threadIdx.x, lane = tid & 63, wave = tid >> 6;

  const float4* qb = (const float4*)(qh + (bh * 2304 + row0) * 16);
  const float4* kb = (const float4*)(kh + (size_t)bh * 2304 * 16);
  const float4* vb = (const float4*)(vh + (size_t)bh * 2304 * 16);

  // ---- gate MLP: keep count (uniform across block) ----
  float eAvg = ent[bh] * (1.f / 2304.f);
  float gacc = bg2[0];
#pragma unroll
  for (int i = 0; i < 16; i++) {
    float h = fmaxf(fmaf(eAvg, Wg1[i], bg1[i]), 0.f);
    gacc = fmaf(h, Wg2[i], gacc);
  }
  float ratio = 0.9f / (1.f + __expf(-gacc)) + 0.1f;
  int kp = (int)ceilf(ratio * 2304.f);
  unsigned keep = (unsigned)min(max(kp, 1), 2304);

  // ---- phase A: logits -> LDS; row max ----
  float4 qq[4][4];
#pragma unroll
  for (int r = 0; r < 4; r++)
#pragma unroll
    for (int p = 0; p < 4; p++) qq[r][p] = qb[r * 4 + p];

  float mloc[4] = {NEG_INF, NEG_INF, NEG_INF, NEG_INF};
#pragma unroll
  for (int jj = 0; jj < 9; jj++) {
    int j = tid + jj * 256;
    float4 k0 = kb[j * 4 + 0], k1 = kb[j * 4 + 1];
    float4 k2 = kb[j * 4 + 2], k3 = kb[j * 4 + 3];
#pragma unroll
    for (int r = 0; r < 4; r++) {
      float v = dot16(qq[r], k0, k1, k2, k3);
      mloc[r] = fmaxf(mloc[r], v);
      aLds[r * 2304 + j] = v;
    }
  }
#pragma unroll
  for (int off = 1; off < 64; off <<= 1)
#pragma unroll
    for (int r = 0; r < 4; r++)
      mloc[r] = fmaxf(mloc[r], __shfl_xor(mloc[r], off));
  if (lane == 0) {
#pragma unroll
    for (int r = 0; r < 4; r++) mSh[wave][r] = mloc[r];
  }
  __syncthreads();
  float m[4];
#pragma unroll
  for (int r = 0; r < 4; r++)
    m[r] = fmaxf(fmaxf(mSh[0][r], mSh[1][r]), fmaxf(mSh[2][r], mSh[3][r]));

  // ---- phase B: row-per-wave exact k-th largest, ballot bit-search ----
  // Early exit: if cnt(key>=cand)==keep, set {key>=cand} == set {key>=kth}
  // (nested, equal size), so the selection mask is already exact.
  {
    int r = wave;  // each wave owns one row
    unsigned keys[36];
    const float* rowp = aLds + r * 2304 + lane;
#pragma unroll
    for (int i = 0; i < 36; i++) keys[i] = f2key(rowp[i * 64]);
    unsigned T = 0u;
    for (int bit = 31; bit >= 0; --bit) {
      unsigned cand = T | (1u << bit);
      unsigned cnt = 0u;
#pragma unroll
      for (int i = 0; i < 36; i++)
        cnt += (unsigned)__popcll(__ballot(keys[i] >= cand));
      if (cnt >= keep) {
        T = cand;  // uniform
        if (cnt == keep) break;
      }
    }
    if (lane == 0) thSh[r] = key2f(T);
  }
  __syncthreads();  // all phase-B LDS reads done; th visible
  float th[4];
#pragma unroll
  for (int r = 0; r < 4; r++) th[r] = thSh[r];

  // ---- phase C1: p = masked exp, in-place into aLds; sp partials ----
  float sp[4] = {0.f, 0.f, 0.f, 0.f};
#pragma unroll
  for (int jj = 0; jj < 9; jj++) {
    int j = tid + jj * 256;
#pragma unroll
    for (int r = 0; r < 4; r++) {
      float av = aLds[r * 2304 + j];
      float p = (av >= th[r]) ? __expf(av - m[r]) : 0.f;
      aLds[r * 2304 + j] = p;
      sp[r] += p;
    }
  }
#pragma unroll
  for (int off = 1; off < 64; off <<= 1)
#pragma unroll
    for (int r = 0; r < 4; r++) sp[r] += __shfl_xor(sp[r], off);
  if (lane == 0) {
#pragma unroll
    for (int r = 0; r < 4; r++) sShW[wave][r] = sp[r];
  }
  __syncthreads();

  // ---- phase C2: dense PV from prob LDS, d-quad split (no exp/cmp) ----
  int dg = tid & 3, jg = tid >> 2;
  float acc[4][4];
#pragma unroll
  for (int r = 0; r < 4; r++)
#pragma unroll
    for (int i = 0; i < 4; i++) acc[r][i] = 0.f;
  for (int jj = 0; jj < 36; jj++) {
    int j = jg + jj * 64;
    float4 v4 = vb[j * 4 + dg];
#pragma unroll
    for (int r = 0; r < 4; r++) {
      float p = aLds[r * 2304 + j];
      acc[r][0] = fmaf(p, v4.x, acc[r][0]);
      acc[r][1] = fmaf(p, v4.y, acc[r][1]);
      acc[r][2] = fmaf(p, v4.z, acc[r][2]);
      acc[r][3] = fmaf(p, v4.w, acc[r][3]);
    }
  }

  // ---- phase D: reduce over 64 j-groups via padded LDS ----
  __syncthreads();  // all aLds prob reads done; safe to reuse as 'part'
  float* part = aLds;  // stride 65 floats per j-group
#pragma unroll
  for (int r = 0; r < 4; r++)
#pragma unroll
    for (int i = 0; i < 4; i++)
      part[jg * 65 + r * 16 + dg * 4 + i] = acc[r][i];
  __syncthreads();
  if (tid < 64) {
    float t2 = 0.f;
    for (int g = 0; g < 64; g++) t2 += part[g * 65 + tid];
    int r = tid >> 4, d = tid & 15;
    float S = sShW[0][r] + sShW[1][r] + sShW[2][r] + sShW[3][r];
    oh[((size_t)(bh * 2304 + row0 + r)) * 16 + d] = t2 / S;
  }
}

// K6: output projection out[b,co,pos] = Wproj @ heads + bproj
__global__ __launch_bounds__(256) void k_proj(const float* __restrict__ oh,
                                              const float* __restrict__ Wp,
                                              const float* __restrict__ bp,
                                              float* __restrict__ out) {
  int blk = blockIdx.x;
  int chunk = blk % 9;
  int co = (blk / 9) % 64;
  int b = blk / (9 * 64);
  int pos = chunk * 256 + threadIdx.x;
  const float* wr = Wp + co * 64;
  float acc = bp[co];
#pragma unroll
  for (int head = 0; head < 4; head++) {
    const float4* op = (const float4*)(oh + ((size_t)((b * 4 + head) * 2304 + pos)) * 16);
#pragma unroll
    for (int p = 0; p < 4; p++) {
      float4 o4 = op[p];
      acc = fmaf(wr[head * 16 + p * 4 + 0], o4.x, acc);
      acc = fmaf(wr[head * 16 + p * 4 + 1], o4.y, acc);
      acc = fmaf(wr[head * 16 + p * 4 + 2], o4.z, acc);
      acc = fmaf(wr[head * 16 + p * 4 + 3], o4.w, acc);
    }
  }
  out[(b * 64 + co) * 2304 + pos] = acc;
}

extern "C" void kernel_launch(void* const* d_in, const int* in_sizes, int n_in,
                              void* d_out, int out_size, void* d_ws,
                              size_t ws_size, hipStream_t stream) {
  const float* x    = (const float*)d_in[0];
  const float* Wqkv = (const float*)d_in[1];
  const float* bqkv = (const float*)d_in[2];
  const float* Wpos = (const float*)d_in[3];
  const float* bpos = (const float*)d_in[4];
  const float* Wg1  = (const float*)d_in[5];
  const float* bg1  = (const float*)d_in[6];
  const float* Wg2  = (const float*)d_in[7];
  const float* bg2  = (const float*)d_in[8];
  const float* Wpr  = (const float*)d_in[9];
  const float* bpr  = (const float*)d_in[10];
  float* out = (float*)d_out;

  float* ws = (float*)d_ws;
  float* qkv_raw = ws;                // 2*192*2304 = 884736
  float* qh = qkv_raw + 884736;       // 294912 (pre-scaled by 0.25)
  float* kh = qh + 294912;            // 294912
  float* vh = kh + 294912;            // 294912
  float* oh = vh + 294912;            // 294912
  float* ent = oh + 294912;           // 8

  hipMemsetAsync(ent, 0, 8 * sizeof(float), stream);
  hipLaunchKernelGGL(k_qkv, dim3(2 * 192 * 9), dim3(256), 0, stream,
                     x, Wqkv, bqkv, qkv_raw);
  hipLaunchKernelGGL(k_dw, dim3(2 * 192 * 9), dim3(256), 0, stream,
                     qkv_raw, Wpos, bpos, qh, kh, vh);
  hipLaunchKernelGGL(k_ent, dim3(8 * 576), dim3(256), 0, stream, qh, kh, ent);
  hipLaunchKernelGGL(k_attn, dim3(8 * 576), dim3(256), 0, stream,
                     qh, kh, vh, ent, Wg1, bg1, Wg2, bg2, oh);
  hipLaunchKernelGGL(k_proj, dim3(2 * 64 * 9), dim3(256), 0, stream,
                     oh, Wpr, bpr, out);
}

// Round 5
// 286.237 us; speedup vs baseline: 1.3537x; 1.0909x over previous
//
#include <hip/hip_runtime.h>
#include <hip/hip_fp16.h>

// Problem sizes (fixed): b=2, c=64, 48x48 -> n=2304, heads=4, hd=16, 3c=192
// n = 2304 = 9*256 exactly.

#define NEG_INF (-__builtin_huge_valf())

// 16-bit monotone key map for half-precision values.
__device__ __forceinline__ unsigned h2key(unsigned short u) {
  return (u & 0x8000u) ? (unsigned)((~u) & 0xFFFFu) : (unsigned)(u | 0x8000u);
}
__device__ __forceinline__ float key16_to_float(unsigned k) {
  unsigned short u = (k & 0x8000u) ? (unsigned short)(k & 0x7FFFu)
                                   : (unsigned short)((~k) & 0xFFFFu);
  return __half2float(__ushort_as_half(u));
}

__device__ __forceinline__ float dot16(const float4* q, float4 k0, float4 k1,
                                       float4 k2, float4 k3) {
  float s = q[0].x * k0.x;
  s = fmaf(q[0].y, k0.y, s); s = fmaf(q[0].z, k0.z, s); s = fmaf(q[0].w, k0.w, s);
  s = fmaf(q[1].x, k1.x, s); s = fmaf(q[1].y, k1.y, s);
  s = fmaf(q[1].z, k1.z, s); s = fmaf(q[1].w, k1.w, s);
  s = fmaf(q[2].x, k2.x, s); s = fmaf(q[2].y, k2.y, s);
  s = fmaf(q[2].z, k2.z, s); s = fmaf(q[2].w, k2.w, s);
  s = fmaf(q[3].x, k3.x, s); s = fmaf(q[3].y, k3.y, s);
  s = fmaf(q[3].z, k3.z, s); s = fmaf(q[3].w, k3.w, s);
  return s;
}

// K1: 1x1 conv qkv = Wqkv @ x + bqkv.  out[b,o,pos], grid = 2*192*9 blocks.
__global__ __launch_bounds__(256) void k_qkv(const float* __restrict__ x,
                                             const float* __restrict__ W,
                                             const float* __restrict__ bias,
                                             float* __restrict__ out) {
  int blk = blockIdx.x;
  int chunk = blk % 9;
  int o = (blk / 9) % 192;
  int b = blk / (9 * 192);
  int pos = chunk * 256 + threadIdx.x;
  const float* xb = x + b * 64 * 2304 + pos;
  const float* wr = W + o * 64;
  float acc = bias[o];
#pragma unroll
  for (int c = 0; c < 64; c++) acc = fmaf(wr[c], xb[c * 2304], acc);
  out[(b * 192 + o) * 2304 + pos] = acc;
}

// K2: 3x3 depthwise conv (SAME) + bias, scatter to head layout.
// q gets *0.25 (softmax scale folded in).
__global__ __launch_bounds__(256) void k_dw(const float* __restrict__ qkv,
                                            const float* __restrict__ Wpos,
                                            const float* __restrict__ bpos,
                                            float* __restrict__ qh,
                                            float* __restrict__ kh,
                                            float* __restrict__ vh) {
  int blk = blockIdx.x;
  int chunk = blk % 9;
  int ch = (blk / 9) % 192;
  int b = blk / (9 * 192);
  int pos = chunk * 256 + threadIdx.x;
  int yy = pos / 48, xx = pos % 48;
  const float* in = qkv + (b * 192 + ch) * 2304;
  const float* w = Wpos + ch * 9;
  float acc = bpos[ch];
#pragma unroll
  for (int dy = -1; dy <= 1; dy++) {
    int y2 = yy + dy;
    if ((unsigned)y2 < 48u) {
#pragma unroll
      for (int dx = -1; dx <= 1; dx++) {
        int x2 = xx + dx;
        if ((unsigned)x2 < 48u)
          acc = fmaf(w[(dy + 1) * 3 + (dx + 1)], in[y2 * 48 + x2], acc);
      }
    }
  }
  int sel = ch >> 6;
  int c = ch & 63;
  int head = c >> 4, d = c & 15;
  if (sel == 0) acc *= 0.25f;  // scale = hd^-0.5 = 0.25 folded into q
  float* dst = (sel == 0) ? qh : ((sel == 1) ? kh : vh);
  dst[((b * 4 + head) * 2304 + pos) * 16 + d] = acc;
}

// K3: entropy of full softmax per row, summed per (b,head) via atomicAdd.
__global__ __launch_bounds__(256) void k_ent(const float* __restrict__ qh,
                                             const float* __restrict__ kh,
                                             float* __restrict__ ent) {
  int blk = blockIdx.x;
  int rowblk = blk % 576;
  int bh = blk / 576;
  int row0 = rowblk * 4;
  int tid = threadIdx.x, lane = tid & 63, wave = tid >> 6;
  const float4* qb = (const float4*)(qh + (bh * 2304 + row0) * 16);
  float4 qq[4][4];
#pragma unroll
  for (int r = 0; r < 4; r++)
#pragma unroll
    for (int p = 0; p < 4; p++) qq[r][p] = qb[r * 4 + p];
  const float4* kb = (const float4*)(kh + (size_t)bh * 2304 * 16);

  float a[4][9];
  float mloc[4] = {NEG_INF, NEG_INF, NEG_INF, NEG_INF};
#pragma unroll
  for (int jj = 0; jj < 9; jj++) {
    int j = tid + jj * 256;
    float4 k0 = kb[j * 4 + 0], k1 = kb[j * 4 + 1];
    float4 k2 = kb[j * 4 + 2], k3 = kb[j * 4 + 3];
#pragma unroll
    for (int r = 0; r < 4; r++) {
      float v = dot16(qq[r], k0, k1, k2, k3);
      a[r][jj] = v;
      mloc[r] = fmaxf(mloc[r], v);
    }
  }
#pragma unroll
  for (int off = 1; off < 64; off <<= 1)
#pragma unroll
    for (int r = 0; r < 4; r++)
      mloc[r] = fmaxf(mloc[r], __shfl_xor(mloc[r], off));

  __shared__ float mSh[4][4], sSh[4][4], uSh[4][4], er[4];
  if (lane == 0) {
#pragma unroll
    for (int r = 0; r < 4; r++) mSh[wave][r] = mloc[r];
  }
  __syncthreads();
  float m[4];
#pragma unroll
  for (int r = 0; r < 4; r++)
    m[r] = fmaxf(fmaxf(mSh[0][r], mSh[1][r]), fmaxf(mSh[2][r], mSh[3][r]));

  float s[4] = {0.f, 0.f, 0.f, 0.f}, u[4] = {0.f, 0.f, 0.f, 0.f};
#pragma unroll
  for (int jj = 0; jj < 9; jj++) {
#pragma unroll
    for (int r = 0; r < 4; r++) {
      float z = a[r][jj] - m[r];
      float e = __expf(z);
      s[r] += e;
      u[r] = fmaf(z, e, u[r]);
    }
  }
#pragma unroll
  for (int off = 1; off < 64; off <<= 1) {
#pragma unroll
    for (int r = 0; r < 4; r++) {
      s[r] += __shfl_xor(s[r], off);
      u[r] += __shfl_xor(u[r], off);
    }
  }
  if (lane == 0) {
#pragma unroll
    for (int r = 0; r < 4; r++) { sSh[wave][r] = s[r]; uSh[wave][r] = u[r]; }
  }
  __syncthreads();
  if (tid < 4) {
    int r = tid;
    float S = sSh[0][r] + sSh[1][r] + sSh[2][r] + sSh[3][r];
    float U = uSh[0][r] + uSh[1][r] + uSh[2][r] + uSh[3][r];
    er[r] = __logf(S) - U / S;
  }
  __syncthreads();
  if (tid == 0) atomicAdd(&ent[bh], er[0] + er[1] + er[2] + er[3]);
}

// K5: gate MLP + per-row exact k-th (16-bit ballot search on f16 logits) +
// masked softmax + PV. Logit/prob matrix in LDS as f16 [j][r] interleaved:
// one b64 access covers all 4 rows at a j. 18.7 KB LDS -> 7-8 blocks/CU.
__global__ __launch_bounds__(256, 7) void k_attn(const float* __restrict__ qh,
                                                 const float* __restrict__ kh,
                                                 const float* __restrict__ vh,
                                                 const float* __restrict__ ent,
                                                 const float* __restrict__ Wg1,
                                                 const float* __restrict__ bg1,
                                                 const float* __restrict__ Wg2,
                                                 const float* __restrict__ bg2,
                                                 float* __restrict__ oh) {
  // 2304 j * 4 rows * 2B = 18432 B; also reused as fp32 reduce buf (16640 B).
  __shared__ __align__(16) unsigned long long ldsRaw[18432 / 8];
  __shared__ float mSh[4][4];
  __shared__ float thSh[4];
  __shared__ float sShW[4][4];

  uint2* lgt64 = (uint2*)ldsRaw;                       // [j] -> 4 halfs
  const unsigned short* lgtU = (const unsigned short*)ldsRaw;  // [j*4+r]

  int blk = blockIdx.x;
  int rowblk = blk % 576;
  int bh = blk / 576;
  int row0 = rowblk * 4;
  int tid = threadIdx.x, lane = tid & 63, wave = tid >> 6;

  const float4* qb = (const float4*)(qh + (bh * 2304 + row0) * 16);
  const float4* kb = (const float4*)(kh + (size_t)bh * 2304 * 16);
  const float4* vb = (const float4*)(vh + (size_t)bh * 2304 * 16);

  // ---- gate MLP: keep count (uniform across block) ----
  float eAvg = ent[bh] * (1.f / 2304.f);
  float gacc = bg2[0];
#pragma unroll
  for (int i = 0; i < 16; i++) {
    float h = fmaxf(fmaf(eAvg, Wg1[i], bg1[i]), 0.f);
    gacc = fmaf(h, Wg2[i], gacc);
  }
  float ratio = 0.9f / (1.f + __expf(-gacc)) + 0.1f;
  int kp = (int)ceilf(ratio * 2304.f);
  unsigned keep = (unsigned)min(max(kp, 1), 2304);

  // ---- phase A: logits -> LDS (f16, [j][r]); row max (fp32) ----
  float4 qq[4][4];
#pragma unroll
  for (int r = 0; r < 4; r++)
#pragma unroll
    for (int p = 0; p < 4; p++) qq[r][p] = qb[r * 4 + p];

  float mloc[4] = {NEG_INF, NEG_INF, NEG_INF, NEG_INF};
#pragma unroll
  for (int jj = 0; jj < 9; jj++) {
    int j = tid + jj * 256;
    float4 k0 = kb[j * 4 + 0], k1 = kb[j * 4 + 1];
    float4 k2 = kb[j * 4 + 2], k3 = kb[j * 4 + 3];
    float v[4];
#pragma unroll
    for (int r = 0; r < 4; r++) {
      v[r] = dot16(qq[r], k0, k1, k2, k3);
      mloc[r] = fmaxf(mloc[r], v[r]);
    }
    __half2 h01 = __floats2half2_rn(v[0], v[1]);
    __half2 h23 = __floats2half2_rn(v[2], v[3]);
    uint2 packed;
    packed.x = *(unsigned*)&h01;
    packed.y = *(unsigned*)&h23;
    lgt64[j] = packed;
  }
#pragma unroll
  for (int off = 1; off < 64; off <<= 1)
#pragma unroll
    for (int r = 0; r < 4; r++)
      mloc[r] = fmaxf(mloc[r], __shfl_xor(mloc[r], off));
  if (lane == 0) {
#pragma unroll
    for (int r = 0; r < 4; r++) mSh[wave][r] = mloc[r];
  }
  __syncthreads();
  float m[4];
#pragma unroll
  for (int r = 0; r < 4; r++)
    m[r] = fmaxf(fmaxf(mSh[0][r], mSh[1][r]), fmaxf(mSh[2][r], mSh[3][r]));

  // ---- phase B: row-per-wave exact k-th largest on 16-bit keys ----
  {
    int r = wave;  // each wave owns one row
    unsigned keys[36];
#pragma unroll
    for (int i = 0; i < 36; i++) {
      int j = lane + i * 64;
      keys[i] = h2key(lgtU[j * 4 + r]);
    }
    unsigned T = 0u;
    for (int bit = 15; bit >= 0; --bit) {
      unsigned cand = T | (1u << bit);
      unsigned cnt = 0u;
#pragma unroll
      for (int i = 0; i < 36; i++)
        cnt += (unsigned)__popcll(__ballot(keys[i] >= cand));
      if (cnt >= keep) {
        T = cand;  // uniform
        if (cnt == keep) break;
      }
    }
    if (lane == 0) thSh[r] = key16_to_float(T);
  }
  __syncthreads();  // all phase-B LDS reads done; th visible
  float th[4];
#pragma unroll
  for (int r = 0; r < 4; r++) th[r] = thSh[r];

  // ---- phase C1: p = masked exp, in-place (f16); sp partials ----
  float sp[4] = {0.f, 0.f, 0.f, 0.f};
#pragma unroll
  for (int jj = 0; jj < 9; jj++) {
    int j = tid + jj * 256;
    uint2 raw = lgt64[j];
    __half2 h01 = *(__half2*)&raw.x;
    __half2 h23 = *(__half2*)&raw.y;
    float2 a01 = __half22float2(h01);
    float2 a23 = __half22float2(h23);
    float av[4] = {a01.x, a01.y, a23.x, a23.y};
    float p[4];
#pragma unroll
    for (int r = 0; r < 4; r++) {
      p[r] = (av[r] >= th[r]) ? __expf(av[r] - m[r]) : 0.f;
      sp[r] += p[r];
    }
    __half2 p01 = __floats2half2_rn(p[0], p[1]);
    __half2 p23 = __floats2half2_rn(p[2], p[3]);
    uint2 packed;
    packed.x = *(unsigned*)&p01;
    packed.y = *(unsigned*)&p23;
    lgt64[j] = packed;
  }
#pragma unroll
  for (int off = 1; off < 64; off <<= 1)
#pragma unroll
    for (int r = 0; r < 4; r++) sp[r] += __shfl_xor(sp[r], off);
  if (lane == 0) {
#pragma unroll
    for (int r = 0; r < 4; r++) sShW[wave][r] = sp[r];
  }
  __syncthreads();

  // ---- phase C2: dense PV from f16 probs, d-quad split ----
  int dg = tid & 3, jg = tid >> 2;
  float acc[4][4];
#pragma unroll
  for (int r = 0; r < 4; r++)
#pragma unroll
    for (int i = 0; i < 4; i++) acc[r][i] = 0.f;
  for (int jj = 0; jj < 36; jj++) {
    int j = jg + jj * 64;
    float4 v4 = vb[j * 4 + dg];
    uint2 raw = lgt64[j];
    float2 p01 = __half22float2(*(__half2*)&raw.x);
    float2 p23 = __half22float2(*(__half2*)&raw.y);
    float p[4] = {p01.x, p01.y, p23.x, p23.y};
#pragma unroll
    for (int r = 0; r < 4; r++) {
      acc[r][0] = fmaf(p[r], v4.x, acc[r][0]);
      acc[r][1] = fmaf(p[r], v4.y, acc[r][1]);
      acc[r][2] = fmaf(p[r], v4.z, acc[r][2]);
      acc[r][3] = fmaf(p[r], v4.w, acc[r][3]);
    }
  }

  // ---- phase D: reduce over 64 j-groups via padded LDS (fp32 view) ----
  __syncthreads();  // all prob reads done; reuse buffer
  float* part = (float*)ldsRaw;  // stride 65 floats per j-group (16640 B)
#pragma unroll
  for (int r = 0; r < 4; r++)
#pragma unroll
    for (int i = 0; i < 4; i++)
      part[jg * 65 + r * 16 + dg * 4 + i] = acc[r][i];
  __syncthreads();
  if (tid < 64) {
    float t2 = 0.f;
    for (int g = 0; g < 64; g++) t2 += part[g * 65 + tid];
    int r = tid >> 4, d = tid & 15;
    float S = sShW[0][r] + sShW[1][r] + sShW[2][r] + sShW[3][r];
    oh[((size_t)(bh * 2304 + row0 + r)) * 16 + d] = t2 / S;
  }
}

// K6: output projection out[b,co,pos] = Wproj @ heads + bproj
__global__ __launch_bounds__(256) void k_proj(const float* __restrict__ oh,
                                              const float* __restrict__ Wp,
                                              const float* __restrict__ bp,
                                              float* __restrict__ out) {
  int blk = blockIdx.x;
  int chunk = blk % 9;
  int co = (blk / 9) % 64;
  int b = blk / (9 * 64);
  int pos = chunk * 256 + threadIdx.x;
  const float* wr = Wp + co * 64;
  float acc = bp[co];
#pragma unroll
  for (int head = 0; head < 4; head++) {
    const float4* op = (const float4*)(oh + ((size_t)((b * 4 + head) * 2304 + pos)) * 16);
#pragma unroll
    for (int p = 0; p < 4; p++) {
      float4 o4 = op[p];
      acc = fmaf(wr[head * 16 + p * 4 + 0], o4.x, acc);
      acc = fmaf(wr[head * 16 + p * 4 + 1], o4.y, acc);
      acc = fmaf(wr[head * 16 + p * 4 + 2], o4.z, acc);
      acc = fmaf(wr[head * 16 + p * 4 + 3], o4.w, acc);
    }
  }
  out[(b * 64 + co) * 2304 + pos] = acc;
}

extern "C" void kernel_launch(void* const* d_in, const int* in_sizes, int n_in,
                              void* d_out, int out_size, void* d_ws,
                              size_t ws_size, hipStream_t stream) {
  const float* x    = (const float*)d_in[0];
  const float* Wqkv = (const float*)d_in[1];
  const float* bqkv = (const float*)d_in[2];
  const float* Wpos = (const float*)d_in[3];
  const float* bpos = (const float*)d_in[4];
  const float* Wg1  = (const float*)d_in[5];
  const float* bg1  = (const float*)d_in[6];
  const float* Wg2  = (const float*)d_in[7];
  const float* bg2  = (const float*)d_in[8];
  const float* Wpr  = (const float*)d_in[9];
  const float* bpr  = (const float*)d_in[10];
  float* out = (float*)d_out;

  float* ws = (float*)d_ws;
  float* qkv_raw = ws;                // 2*192*2304 = 884736
  float* qh = qkv_raw + 884736;       // 294912 (pre-scaled by 0.25)
  float* kh = qh + 294912;            // 294912
  float* vh = kh + 294912;            // 294912
  float* oh = vh + 294912;            // 294912
  float* ent = oh + 294912;           // 8

  (void)hipMemsetAsync(ent, 0, 8 * sizeof(float), stream);
  hipLaunchKernelGGL(k_qkv, dim3(2 * 192 * 9), dim3(256), 0, stream,
                     x, Wqkv, bqkv, qkv_raw);
  hipLaunchKernelGGL(k_dw, dim3(2 * 192 * 9), dim3(256), 0, stream,
                     qkv_raw, Wpos, bpos, qh, kh, vh);
  hipLaunchKernelGGL(k_ent, dim3(8 * 576), dim3(256), 0, stream, qh, kh, ent);
  hipLaunchKernelGGL(k_attn, dim3(8 * 576), dim3(256), 0, stream,
                     qh, kh, vh, ent, Wg1, bg1, Wg2, bg2, oh);
  hipLaunchKernelGGL(k_proj, dim3(2 * 64 * 9), dim3(256), 0, stream,
                     oh, Wpr, bpr, out);
}

// Round 6
// 258.579 us; speedup vs baseline: 1.4985x; 1.1070x over previous
//
#include <hip/hip_runtime.h>
#include <hip/hip_fp16.h>

// Problem sizes (fixed): b=2, c=64, 48x48 -> n=2304, heads=4, hd=16, 3c=192
// n = 2304 = 9*256 exactly.

#define NEG_INF (-__builtin_huge_valf())

// 16-bit monotone key map for half-precision values.
__device__ __forceinline__ unsigned h2key(unsigned short u) {
  return (u & 0x8000u) ? (unsigned)((~u) & 0xFFFFu) : (unsigned)(u | 0x8000u);
}
__device__ __forceinline__ float key16_to_float(unsigned k) {
  unsigned short u = (k & 0x8000u) ? (unsigned short)(k & 0x7FFFu)
                                   : (unsigned short)((~k) & 0xFFFFu);
  return __half2float(__ushort_as_half(u));
}

__device__ __forceinline__ float dot16(const float4* q, float4 k0, float4 k1,
                                       float4 k2, float4 k3) {
  float s = q[0].x * k0.x;
  s = fmaf(q[0].y, k0.y, s); s = fmaf(q[0].z, k0.z, s); s = fmaf(q[0].w, k0.w, s);
  s = fmaf(q[1].x, k1.x, s); s = fmaf(q[1].y, k1.y, s);
  s = fmaf(q[1].z, k1.z, s); s = fmaf(q[1].w, k1.w, s);
  s = fmaf(q[2].x, k2.x, s); s = fmaf(q[2].y, k2.y, s);
  s = fmaf(q[2].z, k2.z, s); s = fmaf(q[2].w, k2.w, s);
  s = fmaf(q[3].x, k3.x, s); s = fmaf(q[3].y, k3.y, s);
  s = fmaf(q[3].z, k3.z, s); s = fmaf(q[3].w, k3.w, s);
  return s;
}

// K1: 1x1 conv qkv = Wqkv @ x + bqkv.  out[b,o,pos], grid = 2*192*9 blocks.
__global__ __launch_bounds__(256) void k_qkv(const float* __restrict__ x,
                                             const float* __restrict__ W,
                                             const float* __restrict__ bias,
                                             float* __restrict__ out) {
  int blk = blockIdx.x;
  int chunk = blk % 9;
  int o = (blk / 9) % 192;
  int b = blk / (9 * 192);
  int pos = chunk * 256 + threadIdx.x;
  const float* xb = x + b * 64 * 2304 + pos;
  const float* wr = W + o * 64;
  float acc = bias[o];
#pragma unroll
  for (int c = 0; c < 64; c++) acc = fmaf(wr[c], xb[c * 2304], acc);
  out[(b * 192 + o) * 2304 + pos] = acc;
}

// K2: 3x3 depthwise conv (SAME) + bias, scatter to head layout.
// q gets *0.25 (softmax scale folded in).
__global__ __launch_bounds__(256) void k_dw(const float* __restrict__ qkv,
                                            const float* __restrict__ Wpos,
                                            const float* __restrict__ bpos,
                                            float* __restrict__ qh,
                                            float* __restrict__ kh,
                                            float* __restrict__ vh) {
  int blk = blockIdx.x;
  int chunk = blk % 9;
  int ch = (blk / 9) % 192;
  int b = blk / (9 * 192);
  int pos = chunk * 256 + threadIdx.x;
  int yy = pos / 48, xx = pos % 48;
  const float* in = qkv + (b * 192 + ch) * 2304;
  const float* w = Wpos + ch * 9;
  float acc = bpos[ch];
#pragma unroll
  for (int dy = -1; dy <= 1; dy++) {
    int y2 = yy + dy;
    if ((unsigned)y2 < 48u) {
#pragma unroll
      for (int dx = -1; dx <= 1; dx++) {
        int x2 = xx + dx;
        if ((unsigned)x2 < 48u)
          acc = fmaf(w[(dy + 1) * 3 + (dx + 1)], in[y2 * 48 + x2], acc);
      }
    }
  }
  int sel = ch >> 6;
  int c = ch & 63;
  int head = c >> 4, d = c & 15;
  if (sel == 0) acc *= 0.25f;  // scale = hd^-0.5 = 0.25 folded into q
  float* dst = (sel == 0) ? qh : ((sel == 1) ? kh : vh);
  dst[((b * 4 + head) * 2304 + pos) * 16 + d] = acc;
}

// K3: entropy of full softmax per row (-> gate), and (STORE) f16 logits to
// global in the [j][r4] uint2 layout k_attn consumes, so QK^T runs ONCE.
// grid = 8*576; blockIdx.x = bh*576 + rowblk (same decomposition as k_attn).
template <bool STORE>
__global__ __launch_bounds__(256) void k_ent_t(const float* __restrict__ qh,
                                               const float* __restrict__ kh,
                                               float* __restrict__ ent,
                                               uint2* __restrict__ lgG) {
  int blk = blockIdx.x;
  int rowblk = blk % 576;
  int bh = blk / 576;
  int row0 = rowblk * 4;
  int tid = threadIdx.x, lane = tid & 63, wave = tid >> 6;
  const float4* qb = (const float4*)(qh + (bh * 2304 + row0) * 16);
  float4 qq[4][4];
#pragma unroll
  for (int r = 0; r < 4; r++)
#pragma unroll
    for (int p = 0; p < 4; p++) qq[r][p] = qb[r * 4 + p];
  const float4* kb = (const float4*)(kh + (size_t)bh * 2304 * 16);

  float a[4][9];
  float mloc[4] = {NEG_INF, NEG_INF, NEG_INF, NEG_INF};
#pragma unroll
  for (int jj = 0; jj < 9; jj++) {
    int j = tid + jj * 256;
    float4 k0 = kb[j * 4 + 0], k1 = kb[j * 4 + 1];
    float4 k2 = kb[j * 4 + 2], k3 = kb[j * 4 + 3];
#pragma unroll
    for (int r = 0; r < 4; r++) {
      float v = dot16(qq[r], k0, k1, k2, k3);
      a[r][jj] = v;
      mloc[r] = fmaxf(mloc[r], v);
    }
    if (STORE) {
      __half2 h01 = __floats2half2_rn(a[0][jj], a[1][jj]);
      __half2 h23 = __floats2half2_rn(a[2][jj], a[3][jj]);
      uint2 packed;
      packed.x = *(unsigned*)&h01;
      packed.y = *(unsigned*)&h23;
      lgG[(size_t)blk * 2304 + j] = packed;
    }
  }
#pragma unroll
  for (int off = 1; off < 64; off <<= 1)
#pragma unroll
    for (int r = 0; r < 4; r++)
      mloc[r] = fmaxf(mloc[r], __shfl_xor(mloc[r], off));

  __shared__ float mSh[4][4], sSh[4][4], uSh[4][4], er[4];
  if (lane == 0) {
#pragma unroll
    for (int r = 0; r < 4; r++) mSh[wave][r] = mloc[r];
  }
  __syncthreads();
  float m[4];
#pragma unroll
  for (int r = 0; r < 4; r++)
    m[r] = fmaxf(fmaxf(mSh[0][r], mSh[1][r]), fmaxf(mSh[2][r], mSh[3][r]));

  float s[4] = {0.f, 0.f, 0.f, 0.f}, u[4] = {0.f, 0.f, 0.f, 0.f};
#pragma unroll
  for (int jj = 0; jj < 9; jj++) {
#pragma unroll
    for (int r = 0; r < 4; r++) {
      float z = a[r][jj] - m[r];
      float e = __expf(z);
      s[r] += e;
      u[r] = fmaf(z, e, u[r]);
    }
  }
#pragma unroll
  for (int off = 1; off < 64; off <<= 1) {
#pragma unroll
    for (int r = 0; r < 4; r++) {
      s[r] += __shfl_xor(s[r], off);
      u[r] += __shfl_xor(u[r], off);
    }
  }
  if (lane == 0) {
#pragma unroll
    for (int r = 0; r < 4; r++) { sSh[wave][r] = s[r]; uSh[wave][r] = u[r]; }
  }
  __syncthreads();
  if (tid < 4) {
    int r = tid;
    float S = sSh[0][r] + sSh[1][r] + sSh[2][r] + sSh[3][r];
    float U = uSh[0][r] + uSh[1][r] + uSh[2][r] + uSh[3][r];
    er[r] = __logf(S) - U / S;
  }
  __syncthreads();
  if (tid == 0) atomicAdd(&ent[bh], er[0] + er[1] + er[2] + er[3]);
}

// K5: gate MLP + per-row exact k-th (16-bit ballot search on f16 logits) +
// masked softmax + PV. CACHED: logits come from lgG (written by k_ent) —
// no QK^T here. Otherwise recompute (fallback if ws too small).
template <bool CACHED>
__global__ __launch_bounds__(256, 7) void k_attn_t(const float* __restrict__ qh,
                                                   const float* __restrict__ kh,
                                                   const float* __restrict__ vh,
                                                   const uint2* __restrict__ lgG,
                                                   const float* __restrict__ ent,
                                                   const float* __restrict__ Wg1,
                                                   const float* __restrict__ bg1,
                                                   const float* __restrict__ Wg2,
                                                   const float* __restrict__ bg2,
                                                   float* __restrict__ oh) {
  // 2304 j * 4 rows * 2B = 18432 B; also reused as fp32 reduce buf (16640 B).
  __shared__ __align__(16) unsigned long long ldsRaw[18432 / 8];
  __shared__ float mSh[4][4];
  __shared__ float thSh[4];
  __shared__ float sShW[4][4];

  uint2* lgt64 = (uint2*)ldsRaw;                       // [j] -> 4 halfs
  const unsigned short* lgtU = (const unsigned short*)ldsRaw;  // [j*4+r]

  int blk = blockIdx.x;
  int rowblk = blk % 576;
  int bh = blk / 576;
  int row0 = rowblk * 4;
  int tid = threadIdx.x, lane = tid & 63, wave = tid >> 6;

  const float4* vb = (const float4*)(vh + (size_t)bh * 2304 * 16);

  // ---- gate MLP: keep count (uniform across block) ----
  float eAvg = ent[bh] * (1.f / 2304.f);
  float gacc = bg2[0];
#pragma unroll
  for (int i = 0; i < 16; i++) {
    float h = fmaxf(fmaf(eAvg, Wg1[i], bg1[i]), 0.f);
    gacc = fmaf(h, Wg2[i], gacc);
  }
  float ratio = 0.9f / (1.f + __expf(-gacc)) + 0.1f;
  int kp = (int)ceilf(ratio * 2304.f);
  unsigned keep = (unsigned)min(max(kp, 1), 2304);

  // ---- phase A: logits -> LDS (f16, [j][r]); row max ----
  float mloc[4] = {NEG_INF, NEG_INF, NEG_INF, NEG_INF};
  if (CACHED) {
    const uint2* src = lgG + (size_t)blk * 2304;
#pragma unroll
    for (int jj = 0; jj < 9; jj++) {
      int j = tid + jj * 256;
      uint2 raw = src[j];
      lgt64[j] = raw;
      float2 a01 = __half22float2(*(__half2*)&raw.x);
      float2 a23 = __half22float2(*(__half2*)&raw.y);
      mloc[0] = fmaxf(mloc[0], a01.x);
      mloc[1] = fmaxf(mloc[1], a01.y);
      mloc[2] = fmaxf(mloc[2], a23.x);
      mloc[3] = fmaxf(mloc[3], a23.y);
    }
  } else {
    const float4* qb = (const float4*)(qh + (bh * 2304 + row0) * 16);
    const float4* kb = (const float4*)(kh + (size_t)bh * 2304 * 16);
    float4 qq[4][4];
#pragma unroll
    for (int r = 0; r < 4; r++)
#pragma unroll
      for (int p = 0; p < 4; p++) qq[r][p] = qb[r * 4 + p];
#pragma unroll
    for (int jj = 0; jj < 9; jj++) {
      int j = tid + jj * 256;
      float4 k0 = kb[j * 4 + 0], k1 = kb[j * 4 + 1];
      float4 k2 = kb[j * 4 + 2], k3 = kb[j * 4 + 3];
      float v[4];
#pragma unroll
      for (int r = 0; r < 4; r++) {
        v[r] = dot16(qq[r], k0, k1, k2, k3);
        mloc[r] = fmaxf(mloc[r], v[r]);
      }
      __half2 h01 = __floats2half2_rn(v[0], v[1]);
      __half2 h23 = __floats2half2_rn(v[2], v[3]);
      uint2 packed;
      packed.x = *(unsigned*)&h01;
      packed.y = *(unsigned*)&h23;
      lgt64[j] = packed;
    }
  }
#pragma unroll
  for (int off = 1; off < 64; off <<= 1)
#pragma unroll
    for (int r = 0; r < 4; r++)
      mloc[r] = fmaxf(mloc[r], __shfl_xor(mloc[r], off));
  if (lane == 0) {
#pragma unroll
    for (int r = 0; r < 4; r++) mSh[wave][r] = mloc[r];
  }
  __syncthreads();
  float m[4];
#pragma unroll
  for (int r = 0; r < 4; r++)
    m[r] = fmaxf(fmaxf(mSh[0][r], mSh[1][r]), fmaxf(mSh[2][r], mSh[3][r]));

  // ---- phase B: row-per-wave exact k-th largest on 16-bit keys ----
  {
    int r = wave;  // each wave owns one row
    unsigned keys[36];
#pragma unroll
    for (int i = 0; i < 36; i++) {
      int j = lane + i * 64;
      keys[i] = h2key(lgtU[j * 4 + r]);
    }
    unsigned T = 0u;
    for (int bit = 15; bit >= 0; --bit) {
      unsigned cand = T | (1u << bit);
      unsigned cnt = 0u;
#pragma unroll
      for (int i = 0; i < 36; i++)
        cnt += (unsigned)__popcll(__ballot(keys[i] >= cand));
      if (cnt >= keep) {
        T = cand;  // uniform
        if (cnt == keep) break;
      }
    }
    if (lane == 0) thSh[r] = key16_to_float(T);
  }
  __syncthreads();  // all phase-B LDS reads done; th visible
  float th[4];
#pragma unroll
  for (int r = 0; r < 4; r++) th[r] = thSh[r];

  // ---- phase C1: p = masked exp, in-place (f16); sp partials ----
  float sp[4] = {0.f, 0.f, 0.f, 0.f};
#pragma unroll
  for (int jj = 0; jj < 9; jj++) {
    int j = tid + jj * 256;
    uint2 raw = lgt64[j];
    __half2 h01 = *(__half2*)&raw.x;
    __half2 h23 = *(__half2*)&raw.y;
    float2 a01 = __half22float2(h01);
    float2 a23 = __half22float2(h23);
    float av[4] = {a01.x, a01.y, a23.x, a23.y};
    float p[4];
#pragma unroll
    for (int r = 0; r < 4; r++) {
      p[r] = (av[r] >= th[r]) ? __expf(av[r] - m[r]) : 0.f;
      sp[r] += p[r];
    }
    __half2 p01 = __floats2half2_rn(p[0], p[1]);
    __half2 p23 = __floats2half2_rn(p[2], p[3]);
    uint2 packed;
    packed.x = *(unsigned*)&p01;
    packed.y = *(unsigned*)&p23;
    lgt64[j] = packed;
  }
#pragma unroll
  for (int off = 1; off < 64; off <<= 1)
#pragma unroll
    for (int r = 0; r < 4; r++) sp[r] += __shfl_xor(sp[r], off);
  if (lane == 0) {
#pragma unroll
    for (int r = 0; r < 4; r++) sShW[wave][r] = sp[r];
  }
  __syncthreads();

  // ---- phase C2: dense PV from f16 probs, d-quad split ----
  int dg = tid & 3, jg = tid >> 2;
  float acc[4][4];
#pragma unroll
  for (int r = 0; r < 4; r++)
#pragma unroll
    for (int i = 0; i < 4; i++) acc[r][i] = 0.f;
  for (int jj = 0; jj < 36; jj++) {
    int j = jg + jj * 64;
    float4 v4 = vb[j * 4 + dg];
    uint2 raw = lgt64[j];
    float2 p01 = __half22float2(*(__half2*)&raw.x);
    float2 p23 = __half22float2(*(__half2*)&raw.y);
    float p[4] = {p01.x, p01.y, p23.x, p23.y};
#pragma unroll
    for (int r = 0; r < 4; r++) {
      acc[r][0] = fmaf(p[r], v4.x, acc[r][0]);
      acc[r][1] = fmaf(p[r], v4.y, acc[r][1]);
      acc[r][2] = fmaf(p[r], v4.z, acc[r][2]);
      acc[r][3] = fmaf(p[r], v4.w, acc[r][3]);
    }
  }

  // ---- phase D: reduce over 64 j-groups via padded LDS (fp32 view) ----
  __syncthreads();  // all prob reads done; reuse buffer
  float* part = (float*)ldsRaw;  // stride 65 floats per j-group (16640 B)
#pragma unroll
  for (int r = 0; r < 4; r++)
#pragma unroll
    for (int i = 0; i < 4; i++)
      part[jg * 65 + r * 16 + dg * 4 + i] = acc[r][i];
  __syncthreads();
  if (tid < 64) {
    float t2 = 0.f;
    for (int g = 0; g < 64; g++) t2 += part[g * 65 + tid];
    int r = tid >> 4, d = tid & 15;
    float S = sShW[0][r] + sShW[1][r] + sShW[2][r] + sShW[3][r];
    oh[((size_t)(bh * 2304 + row0 + r)) * 16 + d] = t2 / S;
  }
}

// K6: output projection out[b,co,pos] = Wproj @ heads + bproj
__global__ __launch_bounds__(256) void k_proj(const float* __restrict__ oh,
                                              const float* __restrict__ Wp,
                                              const float* __restrict__ bp,
                                              float* __restrict__ out) {
  int blk = blockIdx.x;
  int chunk = blk % 9;
  int co = (blk / 9) % 64;
  int b = blk / (9 * 64);
  int pos = chunk * 256 + threadIdx.x;
  const float* wr = Wp + co * 64;
  float acc = bp[co];
#pragma unroll
  for (int head = 0; head < 4; head++) {
    const float4* op = (const float4*)(oh + ((size_t)((b * 4 + head) * 2304 + pos)) * 16);
#pragma unroll
    for (int p = 0; p < 4; p++) {
      float4 o4 = op[p];
      acc = fmaf(wr[head * 16 + p * 4 + 0], o4.x, acc);
      acc = fmaf(wr[head * 16 + p * 4 + 1], o4.y, acc);
      acc = fmaf(wr[head * 16 + p * 4 + 2], o4.z, acc);
      acc = fmaf(wr[head * 16 + p * 4 + 3], o4.w, acc);
    }
  }
  out[(b * 64 + co) * 2304 + pos] = acc;
}

extern "C" void kernel_launch(void* const* d_in, const int* in_sizes, int n_in,
                              void* d_out, int out_size, void* d_ws,
                              size_t ws_size, hipStream_t stream) {
  const float* x    = (const float*)d_in[0];
  const float* Wqkv = (const float*)d_in[1];
  const float* bqkv = (const float*)d_in[2];
  const float* Wpos = (const float*)d_in[3];
  const float* bpos = (const float*)d_in[4];
  const float* Wg1  = (const float*)d_in[5];
  const float* bg1  = (const float*)d_in[6];
  const float* Wg2  = (const float*)d_in[7];
  const float* bg2  = (const float*)d_in[8];
  const float* Wpr  = (const float*)d_in[9];
  const float* bpr  = (const float*)d_in[10];
  float* out = (float*)d_out;

  // f16 logit cache: 8*576 blocks * 2304 j * 8 B = 84,934,656 B
  const size_t lgBytes = (size_t)8 * 576 * 2304 * 8;
  const size_t fltBytes = (size_t)(884736 + 4 * 294912 + 8) * 4;
  bool cached = ws_size >= lgBytes + fltBytes;

  uint2* lgG;
  float* fbase;
  if (cached) {
    lgG = (uint2*)d_ws;
    fbase = (float*)((char*)d_ws + lgBytes);
  } else {
    lgG = nullptr;
    fbase = (float*)d_ws;
  }
  float* qkv_raw = fbase;             // 2*192*2304 = 884736
  float* qh = qkv_raw + 884736;       // 294912 (pre-scaled by 0.25)
  float* kh = qh + 294912;            // 294912
  float* vh = kh + 294912;            // 294912
  float* oh = vh + 294912;            // 294912
  float* ent = oh + 294912;           // 8

  (void)hipMemsetAsync(ent, 0, 8 * sizeof(float), stream);
  hipLaunchKernelGGL(k_qkv, dim3(2 * 192 * 9), dim3(256), 0, stream,
                     x, Wqkv, bqkv, qkv_raw);
  hipLaunchKernelGGL(k_dw, dim3(2 * 192 * 9), dim3(256), 0, stream,
                     qkv_raw, Wpos, bpos, qh, kh, vh);
  if (cached) {
    hipLaunchKernelGGL((k_ent_t<true>), dim3(8 * 576), dim3(256), 0, stream,
                       qh, kh, ent, lgG);
    hipLaunchKernelGGL((k_attn_t<true>), dim3(8 * 576), dim3(256), 0, stream,
                       qh, kh, vh, lgG, ent, Wg1, bg1, Wg2, bg2, oh);
  } else {
    hipLaunchKernelGGL((k_ent_t<false>), dim3(8 * 576), dim3(256), 0, stream,
                       qh, kh, ent, lgG);
    hipLaunchKernelGGL((k_attn_t<false>), dim3(8 * 576), dim3(256), 0, stream,
                       qh, kh, vh, lgG, ent, Wg1, bg1, Wg2, bg2, oh);
  }
  hipLaunchKernelGGL(k_proj, dim3(2 * 64 * 9), dim3(256), 0, stream,
                     oh, Wpr, bpr, out);
}